// Round 3
// baseline (647.260 us; speedup 1.0000x reference)
//
#include <hip/hip_runtime.h>
#include <hip/hip_bf16.h>

// CausalSelfAttention: B=8 T=1024 C=2048 NH=16 HD=128. FP32 I/O, bf16 MFMA.
// R8: attn_fwd gains T14 async-STAGE split (issue next K/V loads before the
// compute phase, drain at next iter's LDS write), T5 setprio around MFMA
// clusters, T13 defer-max (RESCALE_THRESHOLD=8). R7's LDS XOR-swizzle kept.
// GEMMs unchanged (m97 2-phase ceiling; 8-phase 256² rewrite is a future
// round's sync-structure change).
// ws: Wat^T 24M | Wpt^T 8M | Q 32M (y overwrites Q after attn) | [xb 32M].
// d_out: K bf16 | V bf16 until proj GEMM overwrites with fp32 result.

typedef unsigned short u16;
typedef __bf16 bf16x8 __attribute__((ext_vector_type(8)));
typedef float f32x4 __attribute__((ext_vector_type(4)));

#define B_ 8
#define T_ 1024
#define C_ 2048
#define NH 16
#define HD 128
#define BH (B_*NH)

__device__ __forceinline__ u16 f2b(float f){
  __bf16 h = (__bf16)f; return __builtin_bit_cast(u16, h);   // RNE
}
__device__ __forceinline__ unsigned pk2(float x, float y){
  return (unsigned)f2b(x) | ((unsigned)f2b(y) << 16);
}
__device__ __forceinline__ bf16x8 ldfrag(const u16* p){
  uint4 u = *(const uint4*)p; return __builtin_bit_cast(bf16x8, u);
}
__device__ __forceinline__ void glds16(const u16* g, const u16* l){
  __builtin_amdgcn_global_load_lds(
      (const __attribute__((address_space(1))) void*)g,
      (__attribute__((address_space(3))) void*)l, 16, 0, 0);
}

// ---------------- fp32 -> bf16 pack, n4 = n/4 ------------------------------
__global__ __launch_bounds__(256) void cvt_bf16(
    const float4* __restrict__ in, ushort4* __restrict__ outp, int n4)
{
  int i = blockIdx.x*256 + threadIdx.x;
  const int stride = gridDim.x*256;
  for (; i < n4; i += stride){
    float4 f = in[i];
    ushort4 o; o.x = f2b(f.x); o.y = f2b(f.y); o.z = f2b(f.z); o.w = f2b(f.w);
    outp[i] = o;
  }
}

// ---------------- W fp32 [R][C] -> bf16 W^T [C][R], 64x64 tiles --------------
__global__ __launch_bounds__(256) void transpose_cvt(
    const float* __restrict__ in, u16* __restrict__ outp, int R, int C)
{
  __shared__ u16 tile[64][65];
  const int t = threadIdx.x;
  const int r0 = blockIdx.y * 64, c0 = blockIdx.x * 64;
#pragma unroll
  for (int ii = 0; ii < 16; ++ii){
    int idx = t + ii*256; int r = idx >> 6, c = idx & 63;
    tile[r][c] = f2b(in[(size_t)(r0 + r)*C + c0 + c]);
  }
  __syncthreads();
#pragma unroll
  for (int ii = 0; ii < 16; ++ii){
    int idx = t + ii*256; int r = idx >> 6, c = idx & 63;
    outp[(size_t)(c0 + r)*R + r0 + c] = tile[c][r];
  }
}

// ---------------- QKV epilogue (shared): scatter Q/K/V [BH][T][HD] -----------
__device__ __forceinline__ void qkv_epilogue(
    const f32x4 acc[4][4], const float* bias, int bx, int by,
    int wm, int wn, int lq, int ln,
    u16* qb, u16* kb, u16* vb)
{
  const int tensor = bx >> 4, h = bx & 15, b = by >> 3, t0 = (by & 7)*128;
  u16* tb = tensor==0 ? qb : (tensor==1 ? kb : vb);
  u16* op = tb + ((size_t)(b*NH + h)*T_ + t0)*HD;
#pragma unroll
  for (int j=0;j<4;j++){
    const float bv = bias[bx*128 + wn*64 + j*16 + ln];
    const int n = wn*64 + j*16 + ln;
#pragma unroll
    for (int i=0;i<4;i++){
      const int m0 = wm*64 + i*16 + lq*4;      // C/D: row = quad*4 + reg
#pragma unroll
      for (int r=0;r<4;r++)
        op[(size_t)(m0 + r)*HD + n] = f2b(acc[i][j][r] + bv);
    }
  }
}

// ---------------- QKV GEMM, m97 path: A = xb bf16 [8192][2048] (glds);
// B = Wat^T bf16 [6144][2048] (glds). ---------------------------------------
__global__ __launch_bounds__(256,2) void gemm_qkv_bb(
    const u16* __restrict__ Xb, const u16* __restrict__ Wt, const float* __restrict__ bias,
    u16* __restrict__ qb, u16* __restrict__ kb, u16* __restrict__ vb)
{
  __shared__ u16 As[128*32];                   // [m][k]
  __shared__ u16 Bs[128*32];                   // [n][k]
  const int t = threadIdx.x;
  const int bx = blockIdx.x, by = blockIdx.y;
  const int lane = t & 63, wv = t >> 6;
  const int lq = lane >> 4, ln = lane & 15;
  const int wm = wv >> 1, wn = wv & 1;

  // chunk c = pass*256 + t -> row c>>2, k-sub (c&3)*8; LDS dest = base+lane*16
  const int c0 = t, c1 = 256 + t;
  const u16* Ap0 = Xb + (size_t)(by*128 + (c0 >> 2))*2048 + (c0 & 3)*8;
  const u16* Ap1 = Xb + (size_t)(by*128 + (c1 >> 2))*2048 + (c1 & 3)*8;
  const u16* Bp0 = Wt + (size_t)(bx*128 + (c0 >> 2))*2048 + (c0 & 3)*8;
  const u16* Bp1 = Wt + (size_t)(bx*128 + (c1 >> 2))*2048 + (c1 & 3)*8;
  const u16* AsW0 = &As[(wv*64)*8];
  const u16* AsW1 = &As[(256 + wv*64)*8];
  const u16* BsW0 = &Bs[(wv*64)*8];
  const u16* BsW1 = &Bs[(256 + wv*64)*8];

  const f32x4 fz = {0.f,0.f,0.f,0.f};
  f32x4 acc[4][4];
#pragma unroll
  for (int i=0;i<4;i++)
#pragma unroll
    for (int j=0;j<4;j++) acc[i][j] = fz;

  for (int kt = 0; kt < 64; ++kt){
    __syncthreads();
    glds16(Ap0, AsW0); glds16(Ap1, AsW1);
    glds16(Bp0, BsW0); glds16(Bp1, BsW1);
    Ap0 += 32; Ap1 += 32; Bp0 += 32; Bp1 += 32;
    __syncthreads();
    bf16x8 af[4], bf[4];
#pragma unroll
    for (int i=0;i<4;i++) af[i] = ldfrag(&As[(wm*64 + i*16 + ln)*32 + lq*8]);
#pragma unroll
    for (int j=0;j<4;j++) bf[j] = ldfrag(&Bs[(wn*64 + j*16 + ln)*32 + lq*8]);
#pragma unroll
    for (int i=0;i<4;i++)
#pragma unroll
      for (int j=0;j<4;j++)
        acc[i][j] = __builtin_amdgcn_mfma_f32_16x16x32_bf16(af[i], bf[j], acc[i][j], 0,0,0);
  }
  qkv_epilogue(acc, bias, bx, by, wm, wn, lq, ln, qb, kb, vb);
}

// ---------------- QKV GEMM, fallback: A = x fp32 (cvt in staging). ----------
__global__ __launch_bounds__(256,2) void gemm_qkv_f32(
    const float* __restrict__ X, const u16* __restrict__ Wt, const float* __restrict__ bias,
    u16* __restrict__ qb, u16* __restrict__ kb, u16* __restrict__ vb)
{
  __shared__ u16 As[128*32];
  __shared__ u16 Bs[128*32];
  const int t = threadIdx.x;
  const int bx = blockIdx.x, by = blockIdx.y;
  const int lane = t & 63, wv = t >> 6;
  const int lq = lane >> 4, ln = lane & 15;
  const int wm = wv >> 1, wn = wv & 1;

  const int ar = t >> 1, ah = t & 1;
  const float* Ap = X + (size_t)(by*128 + ar)*2048 + ah*16;
  u16* AsW = &As[ar*32 + ah*16];

  const int c0 = t, c1 = 256 + t;
  const u16* Bp0 = Wt + (size_t)(bx*128 + (c0 >> 2))*2048 + (c0 & 3)*8;
  const u16* Bp1 = Wt + (size_t)(bx*128 + (c1 >> 2))*2048 + (c1 & 3)*8;
  const u16* BsW0 = &Bs[(wv*64)*8];
  const u16* BsW1 = &Bs[(256 + wv*64)*8];

  const f32x4 fz = {0.f,0.f,0.f,0.f};
  f32x4 acc[4][4];
#pragma unroll
  for (int i=0;i<4;i++)
#pragma unroll
    for (int j=0;j<4;j++) acc[i][j] = fz;

  for (int kt = 0; kt < 64; ++kt){
    float4 a0 = *(const float4*)(Ap);
    float4 a1 = *(const float4*)(Ap + 4);
    float4 a2 = *(const float4*)(Ap + 8);
    float4 a3 = *(const float4*)(Ap + 12);
    Ap += 32;
    __syncthreads();
    uint4 w0, w1;
    w0.x = pk2(a0.x,a0.y); w0.y = pk2(a0.z,a0.w);
    w0.z = pk2(a1.x,a1.y); w0.w = pk2(a1.z,a1.w);
    w1.x = pk2(a2.x,a2.y); w1.y = pk2(a2.z,a2.w);
    w1.z = pk2(a3.x,a3.y); w1.w = pk2(a3.z,a3.w);
    *(uint4*)(AsW) = w0; *(uint4*)(AsW + 8) = w1;
    glds16(Bp0, BsW0);
    glds16(Bp1, BsW1);
    Bp0 += 32; Bp1 += 32;
    __syncthreads();
    bf16x8 af[4], bf[4];
#pragma unroll
    for (int i=0;i<4;i++) af[i] = ldfrag(&As[(wm*64 + i*16 + ln)*32 + lq*8]);
#pragma unroll
    for (int j=0;j<4;j++) bf[j] = ldfrag(&Bs[(wn*64 + j*16 + ln)*32 + lq*8]);
#pragma unroll
    for (int i=0;i<4;i++)
#pragma unroll
      for (int j=0;j<4;j++)
        acc[i][j] = __builtin_amdgcn_mfma_f32_16x16x32_bf16(af[i], bf[j], acc[i][j], 0,0,0);
  }
  qkv_epilogue(acc, bias, bx, by, wm, wn, lq, ln, qb, kb, vb);
}

// ---------------- proj GEMM: A = y bf16 head-major [BH][T][HD] (glds);
// B = Wpt^T bf16 [2048][2048] (glds); out fp32 [8192][2048].
__global__ __launch_bounds__(256,2) void gemm_proj(
    const u16* __restrict__ Y, const u16* __restrict__ Wt, const float* __restrict__ bias,
    float* __restrict__ outp)
{
  __shared__ u16 As[128*32];
  __shared__ u16 Bs[128*32];
  const int t = threadIdx.x;
  const int bx = blockIdx.x, by = blockIdx.y;
  const int lane = t & 63, wv = t >> 6;
  const int lq = lane >> 4, ln = lane & 15;
  const int wm = wv >> 1, wn = wv & 1;

  const int c0 = t, c1 = 256 + t;
  const int rA0 = by*128 + (c0 >> 2), rA1 = by*128 + (c1 >> 2);
  const u16* Ya0 = Y + ((size_t)((rA0 >> 10)*NH)*T_ + (rA0 & 1023))*HD;
  const u16* Ya1 = Y + ((size_t)((rA1 >> 10)*NH)*T_ + (rA1 & 1023))*HD;
  const int kc0 = (c0 & 3)*8, kc1 = (c1 & 3)*8;
  const u16* AsW0 = &As[(wv*64)*8];
  const u16* AsW1 = &As[(256 + wv*64)*8];

  const u16* Bp0 = Wt + (size_t)(bx*128 + (c0 >> 2))*2048 + (c0 & 3)*8;
  const u16* Bp1 = Wt + (size_t)(bx*128 + (c1 >> 2))*2048 + (c1 & 3)*8;
  const u16* BsW0 = &Bs[(wv*64)*8];
  const u16* BsW1 = &Bs[(256 + wv*64)*8];

  const f32x4 fz = {0.f,0.f,0.f,0.f};
  f32x4 acc[4][4];
#pragma unroll
  for (int i=0;i<4;i++)
#pragma unroll
    for (int j=0;j<4;j++) acc[i][j] = fz;

  for (int kt = 0; kt < 64; ++kt){
    __syncthreads();
    {
      const int k0 = kt*32 + kc0, k1 = kt*32 + kc1;    // head = k>>7, d = k&127
      glds16(Ya0 + (size_t)(k0 >> 7)*(T_*HD) + (k0 & 127), AsW0);
      glds16(Ya1 + (size_t)(k1 >> 7)*(T_*HD) + (k1 & 127), AsW1);
      glds16(Bp0, BsW0);
      glds16(Bp1, BsW1);
      Bp0 += 32; Bp1 += 32;
    }
    __syncthreads();
    bf16x8 af[4], bf[4];
#pragma unroll
    for (int i=0;i<4;i++) af[i] = ldfrag(&As[(wm*64 + i*16 + ln)*32 + lq*8]);
#pragma unroll
    for (int j=0;j<4;j++) bf[j] = ldfrag(&Bs[(wn*64 + j*16 + ln)*32 + lq*8]);
#pragma unroll
    for (int i=0;i<4;i++)
#pragma unroll
      for (int j=0;j<4;j++)
        acc[i][j] = __builtin_amdgcn_mfma_f32_16x16x32_bf16(af[i], bf[j], acc[i][j], 0,0,0);
  }

  float* op = outp + (size_t)(by*128)*2048 + bx*128;
#pragma unroll
  for (int j=0;j<4;j++){
    const float bv = bias[bx*128 + wn*64 + j*16 + ln];
    const int n = wn*64 + j*16 + ln;
#pragma unroll
    for (int i=0;i<4;i++){
      const int m0 = wm*64 + i*16 + lq*4;
#pragma unroll
      for (int r=0;r<4;r++)
        op[(size_t)(m0 + r)*2048 + n] = acc[i][j][r] + bv;
    }
  }
}

// ---------------- flash attention. qy: Q in, y out (same buffer, block-disjoint
// tiles). k,v bf16 [BH][T][HD]; V transposed to [d][key] in LDS during staging.
// LDS XOR-swizzled (R7). R8: T14 async-STAGE (next tile's global loads issued
// before compute, drained at next iter's ds_write), T5 setprio around MFMA,
// T13 defer-max (THR=8: skip O-rescale when tile max grew < 8).
// Heavy q-tiles first: qt = 7 - blockIdx.x.
__global__ __launch_bounds__(256,2) void attn_fwd(
    u16* qy, const u16* __restrict__ kk, const u16* __restrict__ vv)
{
  __shared__ u16 Ks[64*128];                   // [key][d], swizzled
  __shared__ u16 Vt[128*64];                   // [d][key], swizzled
  __shared__ u16 Ps[4*32*64];                  // per-wave P strip, swizzled
  const int qt = 7 - blockIdx.x, bh = blockIdx.y;
  const int t = threadIdx.x;
  const int lane = t & 63, wv = t >> 6;
  const int lq = lane >> 4, ln = lane & 15;

  bf16x8 qf[2][4];                             // A-frag: m=lane&15, k=quad*8+j
#pragma unroll
  for (int i=0;i<2;i++)
#pragma unroll
    for (int kc=0;kc<4;kc++){
      int qrow = qt*128 + wv*32 + i*16 + ln;
      qf[i][kc] = ldfrag(&qy[((size_t)bh*T_ + qrow)*HD + kc*32 + lq*8]);
    }

  const f32x4 fz = {0.f,0.f,0.f,0.f};
  f32x4 o[2][8];
#pragma unroll
  for (int i=0;i<2;i++)
#pragma unroll
    for (int jd=0;jd<8;jd++) o[i][jd] = fz;
  float mi[2][4], li[2][4];
#pragma unroll
  for (int i=0;i<2;i++)
#pragma unroll
    for (int r=0;r<4;r++){ mi[i][r] = -1e30f; li[i][r] = 0.f; }

  const float scale = 0.08838834764831843f;    // 1/sqrt(128)
  const int kr = t & 63, dbase = (t >> 6)*32;  // V-transpose stage mapping
  const int nkt = 2*qt + 2;                    // causal: keys < (qt+1)*128

  // T14 prologue: issue tile-0 loads; drained at the first ds_write below.
  uint4 kreg[4];
  uint4 vreg[4];
  {
    const uint4* ksrc = (const uint4*)(kk + (size_t)bh*T_*HD);
#pragma unroll
    for (int ii=0; ii<4; ++ii) kreg[ii] = ksrc[t + ii*256];
#pragma unroll
    for (int ch=0; ch<4; ++ch)
      vreg[ch] = *(const uint4*)&vv[((size_t)bh*T_ + kr)*HD + dbase + ch*8];
  }

  for (int kt = 0; kt < nkt; ++kt){
    __syncthreads();                           // prior iter done reading Ks/Vt
    uint4* kdst = (uint4*)Ks;
#pragma unroll
    for (int ii=0; ii<4; ++ii){
      const int c = t + ii*256;                // chunk: row c>>4, slot c&15
      kdst[(c & ~15) | ((c & 15) ^ ((c >> 4) & 7))] = kreg[ii];
    }
#pragma unroll
    for (int ch=0; ch<4; ++ch){
      const u16* e = (const u16*)&vreg[ch];
#pragma unroll
      for (int j=0; j<8; ++j){
        const int d = dbase + ch*8 + j;
        Vt[d*64 + (kr ^ ((d & 7) << 3))] = e[j]; // distinct cols/lane: free
      }
    }
    __syncthreads();

    // T14: issue next tile's loads now; HBM latency hides under QK^T/SM/PV.
    // (ds_writes above already consumed kreg/vreg at issue - WAR is safe.)
    {
      const int ktn = (kt+1 < nkt) ? kt+1 : kt;   // last iter: harmless reload
      const uint4* ksrc = (const uint4*)(kk + ((size_t)bh*T_ + ktn*64)*HD);
#pragma unroll
      for (int ii=0; ii<4; ++ii) kreg[ii] = ksrc[t + ii*256];
#pragma unroll
      for (int ch=0; ch<4; ++ch)
        vreg[ch] = *(const uint4*)&vv[((size_t)bh*T_ + ktn*64 + kr)*HD + dbase + ch*8];
    }

    // S = Q K^T
    f32x4 s[2][4];
#pragma unroll
    for (int i=0;i<2;i++)
#pragma unroll
      for (int j=0;j<4;j++) s[i][j] = fz;
    __builtin_amdgcn_s_setprio(1);
#pragma unroll
    for (int j=0;j<4;j++){
      bf16x8 kf[4];                            // B-frag: n=key, k=d
      const int krow = j*16 + ln;
      const int ksw = (krow & 7) << 3;
#pragma unroll
      for (int kc=0;kc<4;kc++)
        kf[kc] = ldfrag(&Ks[krow*128 + ((kc*32 + lq*8) ^ ksw)]);
#pragma unroll
      for (int i=0;i<2;i++)
#pragma unroll
        for (int kc=0;kc<4;kc++)
          s[i][j] = __builtin_amdgcn_mfma_f32_16x16x32_bf16(qf[i][kc], kf[kc], s[i][j], 0,0,0);
    }
    __builtin_amdgcn_s_setprio(0);

    // scale + causal mask (C/D: row=quad*4+r, col=lane&15)
#pragma unroll
    for (int i=0;i<2;i++)
#pragma unroll
      for (int j=0;j<4;j++)
#pragma unroll
        for (int r=0;r<4;r++){
          int qg = qt*128 + wv*32 + i*16 + lq*4 + r;
          int kg = kt*64 + j*16 + ln;
          float sv = s[i][j][r]*scale;
          s[i][j][r] = (kg > qg) ? -1e30f : sv;
        }

    // online softmax, T13 defer-max: row-max phase first, then a wave-uniform
    // skip of the O-rescale when no row's max grew by more than THR=8.
    float mxv[2][4];
#pragma unroll
    for (int i=0;i<2;i++)
#pragma unroll
      for (int r=0;r<4;r++){
        float mx = fmaxf(fmaxf(s[i][0][r], s[i][1][r]), fmaxf(s[i][2][r], s[i][3][r]));
        mx = fmaxf(mx, __shfl_xor(mx, 1));
        mx = fmaxf(mx, __shfl_xor(mx, 2));
        mx = fmaxf(mx, __shfl_xor(mx, 4));
        mx = fmaxf(mx, __shfl_xor(mx, 8));
        mxv[i][r] = mx;
      }
    bool ok = true;
#pragma unroll
    for (int i=0;i<2;i++)
#pragma unroll
      for (int r=0;r<4;r++) ok = ok && (mxv[i][r] <= mi[i][r] + 8.0f);
    if (!__all((int)ok)){
#pragma unroll
      for (int i=0;i<2;i++)
#pragma unroll
        for (int r=0;r<4;r++){
          float mnew = fmaxf(mi[i][r], mxv[i][r]);
          float alpha = __expf(mi[i][r] - mnew);
          li[i][r] *= alpha;
          mi[i][r] = mnew;
#pragma unroll
          for (int jd=0;jd<8;jd++) o[i][jd][r] *= alpha;
        }
    }
#pragma unroll
    for (int i=0;i<2;i++)
#pragma unroll
      for (int r=0;r<4;r++){
        float rs = 0.f;
#pragma unroll
        for (int j=0;j<4;j++){
          float p = __expf(s[i][j][r] - mi[i][r]);   // bounded by e^8
          s[i][j][r] = p; rs += p;
        }
        rs += __shfl_xor(rs, 1); rs += __shfl_xor(rs, 2);
        rs += __shfl_xor(rs, 4); rs += __shfl_xor(rs, 8);
        li[i][r] += rs;
      }

    // P: C-layout -> per-wave LDS strip (swizzled) -> A-layout frags
#pragma unroll
    for (int i=0;i<2;i++)
#pragma unroll
      for (int j=0;j<4;j++)
#pragma unroll
        for (int r=0;r<4;r++){
          const int rr = i*16 + lq*4 + r;
          Ps[wv*2048 + rr*64 + ((j*16 + ln) ^ ((rr & 7) << 3))] = f2b(s[i][j][r]);
        }

    bf16x8 pf[2][2];
#pragma unroll
    for (int i=0;i<2;i++){
      const int prow = i*16 + ln;
      const int psw = (prow & 7) << 3;
#pragma unroll
      for (int kc=0;kc<2;kc++)
        pf[i][kc] = ldfrag(&Ps[wv*2048 + prow*64 + ((kc*32 + lq*8) ^ psw)]);
    }
    __builtin_amdgcn_s_setprio(1);
#pragma unroll
    for (int jd=0;jd<8;jd++){
      const int vrow = jd*16 + ln;
      const int vsw = (vrow & 7) << 3;
#pragma unroll
      for (int kc=0;kc<2;kc++){
        bf16x8 vf = ldfrag(&Vt[vrow*64 + ((kc*32 + lq*8) ^ vsw)]);
#pragma unroll
        for (int i=0;i<2;i++)
          o[i][jd] = __builtin_amdgcn_mfma_f32_16x16x32_bf16(pf[i][kc], vf, o[i][jd], 0,0,0);
      }
    }
    __builtin_amdgcn_s_setprio(0);
  }

  // epilogue: y over own Q tile, head-major [BH][T][HD]
#pragma unroll
  for (int i=0;i<2;i++)
#pragma unroll
    for (int r=0;r<4;r++){
      float inv = 1.f / li[i][r];
      int row = qt*128 + wv*32 + i*16 + lq*4 + r;
#pragma unroll
      for (int jd=0;jd<8;jd++)
        qy[((size_t)bh*T_ + row)*HD + jd*16 + ln] = f2b(o[i][jd][r] * inv);
    }
}

extern "C" void kernel_launch(void* const* d_in, const int* in_sizes, int n_in,
                              void* d_out, int out_size, void* d_ws, size_t ws_size,
                              hipStream_t stream)
{
  const float* x      = (const float*)d_in[0];   // [8192][2048] fp32
  const float* W_attn = (const float*)d_in[1];   // [2048][6144] fp32
  const float* b_attn = (const float*)d_in[2];   // [6144] fp32
  const float* W_proj = (const float*)d_in[3];   // [2048][2048] fp32
  const float* b_proj = (const float*)d_in[4];   // [2048] fp32
  float* out = (float*)d_out;                    // [8192][2048] fp32

  u16* Wat = (u16*)d_ws;                         // [6144][2048] bf16 = W_attn^T
  u16* Wpt = Wat + (size_t)6144*2048;            // [2048][2048] bf16 = W_proj^T
  u16* qb  = Wpt + (size_t)2048*2048;            // Q bf16, then y bf16
  u16* xb  = qb  + (size_t)BH*T_*HD;             // x bf16 (only if ws >= 96 MiB)
  u16* kb  = (u16*)d_out;                        // K bf16 (d_out low half)
  u16* vb  = kb + (size_t)BH*T_*HD;              // V bf16 (d_out high half)

  const size_t need = ((size_t)6144*2048 + (size_t)2048*2048
                       + 2*(size_t)BH*T_*HD) * sizeof(u16);   // 96 MiB

  hipLaunchKernelGGL(transpose_cvt, dim3(96,32,1), dim3(256,1,1), 0, stream,
                     W_attn, Wat, 2048, 6144);
  hipLaunchKernelGGL(transpose_cvt, dim3(32,32,1), dim3(256,1,1), 0, stream,
                     W_proj, Wpt, 2048, 2048);
  if (ws_size >= need){
    hipLaunchKernelGGL(cvt_bf16, dim3(1024,1,1), dim3(256,1,1), 0, stream,
                       (const float4*)x, (ushort4*)xb, (B_*T_*C_)/4);
    hipLaunchKernelGGL(gemm_qkv_bb, dim3(48,64,1), dim3(256,1,1), 0, stream,
                       xb, Wat, b_attn, qb, kb, vb);
  } else {
    hipLaunchKernelGGL(gemm_qkv_f32, dim3(48,64,1), dim3(256,1,1), 0, stream,
                       x, Wat, b_attn, qb, kb, vb);
  }
  hipLaunchKernelGGL(attn_fwd, dim3(8,BH,1), dim3(256,1,1), 0, stream,
                     qb, kb, vb);
  hipLaunchKernelGGL(gemm_proj, dim3(16,64,1), dim3(256,1,1), 0, stream,
                     qb, Wpt, b_proj, out);
}

// Round 4
// 627.820 us; speedup vs baseline: 1.0310x; 1.0310x over previous
//
#include <hip/hip_runtime.h>
#include <hip/hip_bf16.h>

// CausalSelfAttention: B=8 T=1024 C=2048 NH=16 HD=128. FP32 I/O, bf16 MFMA.
// R9: QKV GEMM rewritten as 256x256 8-phase counted-vmcnt kernel (T3+T4+T2+T5,
// m201 template re-derived): 8 waves, BK=64, 128KiB LDS 2-tile dbuf, 4
// barrier-phases/K-tile, one vmcnt(6) per K-tile (never 0 in steady state),
// XOR-swizzled LDS via pre-swizzled glds sources. Stage schedule proven
// WAR-free: tile T staged at (T-2,+1..+3),(T-1,+0); B-reads end +0, A-reads
// end +1, phase+3 reuses registers.
// attn (R7 swizzle + R8 neutral extras) and proj GEMM unchanged.
// ws: Wat^T 24M | Wpt^T 8M | Q 32M (y overwrites Q after attn) | [xb 32M].
// d_out: K bf16 | V bf16 until proj GEMM overwrites with fp32 result.

typedef unsigned short u16;
typedef __bf16 bf16x8 __attribute__((ext_vector_type(8)));
typedef float f32x4 __attribute__((ext_vector_type(4)));

#define B_ 8
#define T_ 1024
#define C_ 2048
#define NH 16
#define HD 128
#define BH (B_*NH)

__device__ __forceinline__ u16 f2b(float f){
  __bf16 h = (__bf16)f; return __builtin_bit_cast(u16, h);   // RNE
}
__device__ __forceinline__ unsigned pk2(float x, float y){
  return (unsigned)f2b(x) | ((unsigned)f2b(y) << 16);
}
__device__ __forceinline__ bf16x8 ldfrag(const u16* p){
  uint4 u = *(const uint4*)p; return __builtin_bit_cast(bf16x8, u);
}
__device__ __forceinline__ void glds16(const u16* g, const u16* l){
  __builtin_amdgcn_global_load_lds(
      (const __attribute__((address_space(1))) void*)g,
      (__attribute__((address_space(3))) void*)l, 16, 0, 0);
}
__device__ __forceinline__ void sbar(){
  __builtin_amdgcn_sched_barrier(0);
  __builtin_amdgcn_s_barrier();
  __builtin_amdgcn_sched_barrier(0);
}

// ---------------- fp32 -> bf16 pack, n4 = n/4 ------------------------------
__global__ __launch_bounds__(256) void cvt_bf16(
    const float4* __restrict__ in, ushort4* __restrict__ outp, int n4)
{
  int i = blockIdx.x*256 + threadIdx.x;
  const int stride = gridDim.x*256;
  for (; i < n4; i += stride){
    float4 f = in[i];
    ushort4 o; o.x = f2b(f.x); o.y = f2b(f.y); o.z = f2b(f.z); o.w = f2b(f.w);
    outp[i] = o;
  }
}

// ---------------- W fp32 [R][C] -> bf16 W^T [C][R], 64x64 tiles --------------
__global__ __launch_bounds__(256) void transpose_cvt(
    const float* __restrict__ in, u16* __restrict__ outp, int R, int C)
{
  __shared__ u16 tile[64][65];
  const int t = threadIdx.x;
  const int r0 = blockIdx.y * 64, c0 = blockIdx.x * 64;
#pragma unroll
  for (int ii = 0; ii < 16; ++ii){
    int idx = t + ii*256; int r = idx >> 6, c = idx & 63;
    tile[r][c] = f2b(in[(size_t)(r0 + r)*C + c0 + c]);
  }
  __syncthreads();
#pragma unroll
  for (int ii = 0; ii < 16; ++ii){
    int idx = t + ii*256; int r = idx >> 6, c = idx & 63;
    outp[(size_t)(c0 + r)*R + r0 + c] = tile[c][r];
  }
}

// ---------------- QKV epilogue for 128-tile fallback path -------------------
__device__ __forceinline__ void qkv_epilogue(
    const f32x4 acc[4][4], const float* bias, int bx, int by,
    int wm, int wn, int lq, int ln,
    u16* qb, u16* kb, u16* vb)
{
  const int tensor = bx >> 4, h = bx & 15, b = by >> 3, t0 = (by & 7)*128;
  u16* tb = tensor==0 ? qb : (tensor==1 ? kb : vb);
  u16* op = tb + ((size_t)(b*NH + h)*T_ + t0)*HD;
#pragma unroll
  for (int j=0;j<4;j++){
    const float bv = bias[bx*128 + wn*64 + j*16 + ln];
    const int n = wn*64 + j*16 + ln;
#pragma unroll
    for (int i=0;i<4;i++){
      const int m0 = wm*64 + i*16 + lq*4;      // C/D: row = quad*4 + reg
#pragma unroll
      for (int r=0;r<4;r++)
        op[(size_t)(m0 + r)*HD + n] = f2b(acc[i][j][r] + bv);
    }
  }
}

// ---------------- QKV GEMM, R9 main path: 256x256 tile, BK=64, 8 waves,
// 8-phase-per-2-K-tiles counted-vmcnt schedule. A = xb bf16 [8192][2048],
// B = Wat^T bf16 [6144][2048], both K-contiguous, staged via glds with
// pre-swizzled sources (slot ^= row&7 at 16B granularity). ------------------
__global__ __launch_bounds__(512,2) void gemm_qkv_8p(
    const u16* __restrict__ Xb, const u16* __restrict__ Wt,
    const float* __restrict__ bias,
    u16* __restrict__ qb, u16* __restrict__ kb, u16* __restrict__ vb)
{
  __shared__ u16 lds[2][2][256*64];            // [buf][A/B][row][k] 128 KiB
  const int t = threadIdx.x;                   // 0..511
  const int lane = t & 63, wid = t >> 6;       // 8 waves: 2M x 4N
  const int lq = lane >> 4, ln = lane & 15;
  const int wm = wid >> 2, wn = wid & 3;

  // XCD-aware swizzle (768 blocks, 768%8==0 -> simple form is bijective)
  const int bid0 = blockIdx.x;
  const int bid = (bid0 & 7)*96 + (bid0 >> 3);
  const int bx = bid % 24, by = bid / 24;      // bx: N/256, by: M/256

  // staging: per wave 2 glds per half-tile (128 rows x 64 k).
  // load q covers rows wid*16 + q*8 + (lane>>3); LDS dest linear; global
  // source pre-swizzled: slot = (lane&7) ^ (row&7).
  const int rl  = (wid << 4) + (lane >> 3);    // q=0 local row (0..127)
  const int sw0 = (lane & 7) ^ (rl & 7);
  const int sw1 = (lane & 7) ^ ((rl + 8) & 7);
  const u16* Ag = Xb + ((size_t)(by*256) + rl)*2048;
  const u16* Bg = Wt + ((size_t)(bx*256) + rl)*2048;
  const size_t q0off = (size_t)sw0*8;
  const size_t q1off = (size_t)8*2048 + (size_t)sw1*8;

#define STAGE(buf_, op_, h_, T_) do { \
    const u16* s_ = (op_ ? Bg : Ag) + (size_t)(h_)*(128*2048) + (size_t)(T_)*64; \
    const u16* d_ = &lds[buf_][op_][(((h_)*128) + (wid<<4))*64]; \
    glds16(s_ + q0off, d_); \
    glds16(s_ + q1off, d_ + 8*64); \
  } while(0)

  // read-side swizzled 16B-slot per ks (row&7 == ln&7 since frag rows = f*16+ln)
  const int swr0 = (0*4 + lq) ^ (ln & 7);
  const int swr1 = (1*4 + lq) ^ (ln & 7);

  const f32x4 fz = {0.f,0.f,0.f,0.f};
  f32x4 acc[8][4];
#pragma unroll
  for (int f=0;f<8;f++)
#pragma unroll
    for (int g=0;g<4;g++) acc[f][g] = fz;

  // prologue: tile0 fully + tile1's Bhi,Blo,Ahi (Alo(1) comes at (0,+0))
  STAGE(0,0,0,0); STAGE(0,0,1,0); STAGE(0,1,0,0); STAGE(0,1,1,0);
  STAGE(1,1,0,1); STAGE(1,1,1,1); STAGE(1,0,0,1);
  asm volatile("s_waitcnt vmcnt(6)" ::: "memory");   // tile0 landed
  sbar();

  for (int T = 0; T < 32; ++T){
    const int b = T & 1;
    const u16* As = lds[b][0];
    const u16* Bs = lds[b][1];
    bf16x8 a0[4][2], a4[4][2], bfr[4][2];

    // ---- phase +0: read A frags 0-3 + all B frags; stage Alo(T+1)
#pragma unroll
    for (int f=0;f<4;f++){
      a0[f][0]  = ldfrag(&As[(wm*128 + f*16 + ln)*64 + swr0*8]);
      a0[f][1]  = ldfrag(&As[(wm*128 + f*16 + ln)*64 + swr1*8]);
      bfr[f][0] = ldfrag(&Bs[(wn*64  + f*16 + ln)*64 + swr0*8]);
      bfr[f][1] = ldfrag(&Bs[(wn*64  + f*16 + ln)*64 + swr1*8]);
    }
    if (T+1 < 32) STAGE(b^1, 0, 1, T+1);
    sbar();
    __builtin_amdgcn_s_setprio(1);
#pragma unroll
    for (int f=0;f<4;f++)
#pragma unroll
      for (int g=0;g<2;g++){
        acc[f][g] = __builtin_amdgcn_mfma_f32_16x16x32_bf16(a0[f][0], bfr[g][0], acc[f][g], 0,0,0);
        acc[f][g] = __builtin_amdgcn_mfma_f32_16x16x32_bf16(a0[f][1], bfr[g][1], acc[f][g], 0,0,0);
      }
    __builtin_amdgcn_s_setprio(0);
    sbar();

    // ---- phase +1: read A frags 4-7; stage Bhi(T+2)
#pragma unroll
    for (int f=0;f<4;f++){
      a4[f][0] = ldfrag(&As[(wm*128 + (f+4)*16 + ln)*64 + swr0*8]);
      a4[f][1] = ldfrag(&As[(wm*128 + (f+4)*16 + ln)*64 + swr1*8]);
    }
    if (T+2 < 32) STAGE(b, 1, 0, T+2);
    sbar();
    __builtin_amdgcn_s_setprio(1);
#pragma unroll
    for (int f=0;f<4;f++)
#pragma unroll
      for (int g=0;g<2;g++){
        acc[f+4][g] = __builtin_amdgcn_mfma_f32_16x16x32_bf16(a4[f][0], bfr[g][0], acc[f+4][g], 0,0,0);
        acc[f+4][g] = __builtin_amdgcn_mfma_f32_16x16x32_bf16(a4[f][1], bfr[g][1], acc[f+4][g], 0,0,0);
      }
    __builtin_amdgcn_s_setprio(0);
    sbar();

    // ---- phase +2: no reads; stage Blo(T+2)
    if (T+2 < 32) STAGE(b, 1, 1, T+2);
    sbar();
    __builtin_amdgcn_s_setprio(1);
#pragma unroll
    for (int f=0;f<4;f++)
#pragma unroll
      for (int g=2;g<4;g++){
        acc[f+4][g] = __builtin_amdgcn_mfma_f32_16x16x32_bf16(a4[f][0], bfr[g][0], acc[f+4][g], 0,0,0);
        acc[f+4][g] = __builtin_amdgcn_mfma_f32_16x16x32_bf16(a4[f][1], bfr[g][1], acc[f+4][g], 0,0,0);
      }
    __builtin_amdgcn_s_setprio(0);
    sbar();

    // ---- phase +3: no reads; stage Ahi(T+2); counted vmcnt
    if (T+2 < 32) STAGE(b, 0, 0, T+2);
    if (T >= 30) asm volatile("s_waitcnt vmcnt(0)" ::: "memory");
    else         asm volatile("s_waitcnt vmcnt(6)" ::: "memory");
    sbar();
    __builtin_amdgcn_s_setprio(1);
#pragma unroll
    for (int f=0;f<4;f++)
#pragma unroll
      for (int g=2;g<4;g++){
        acc[f][g] = __builtin_amdgcn_mfma_f32_16x16x32_bf16(a0[f][0], bfr[g][0], acc[f][g], 0,0,0);
        acc[f][g] = __builtin_amdgcn_mfma_f32_16x16x32_bf16(a0[f][1], bfr[g][1], acc[f][g], 0,0,0);
      }
    __builtin_amdgcn_s_setprio(0);
    sbar();
  }
#undef STAGE

  // epilogue: scatter to Q/K/V [BH][T][HD]; block N-range (256) lies in one
  // tensor (2048 % 256 == 0).
  const int tensor = bx >> 3;
  u16* tb = tensor==0 ? qb : (tensor==1 ? kb : vb);
  const int m_base = by*256 + wm*128;
#pragma unroll
  for (int g=0; g<4; ++g){
    const int ncol = (bx & 7)*256 + wn*64 + g*16 + ln;   // 0..2047 in tensor
    const float bv = bias[tensor*2048 + ncol];
    const int h = ncol >> 7, d = ncol & 127;
#pragma unroll
    for (int f=0; f<8; ++f){
      const int m0 = m_base + f*16 + lq*4;
      const int bb = m0 >> 10, tt = m0 & 1023;           // rows m0..m0+3 same b
      u16* op = tb + ((size_t)(bb*NH + h)*T_ + tt)*HD + d;
#pragma unroll
      for (int r=0;r<4;++r)
        op[(size_t)r*HD] = f2b(acc[f][g][r] + bv);
    }
  }
}

// ---------------- QKV GEMM, fallback: A = x fp32 (cvt in staging). ----------
__global__ __launch_bounds__(256,2) void gemm_qkv_f32(
    const float* __restrict__ X, const u16* __restrict__ Wt, const float* __restrict__ bias,
    u16* __restrict__ qb, u16* __restrict__ kb, u16* __restrict__ vb)
{
  __shared__ u16 As[128*32];
  __shared__ u16 Bs[128*32];
  const int t = threadIdx.x;
  const int bx = blockIdx.x, by = blockIdx.y;
  const int lane = t & 63, wv = t >> 6;
  const int lq = lane >> 4, ln = lane & 15;
  const int wm = wv >> 1, wn = wv & 1;

  const int ar = t >> 1, ah = t & 1;
  const float* Ap = X + (size_t)(by*128 + ar)*2048 + ah*16;
  u16* AsW = &As[ar*32 + ah*16];

  const int c0 = t, c1 = 256 + t;
  const u16* Bp0 = Wt + (size_t)(bx*128 + (c0 >> 2))*2048 + (c0 & 3)*8;
  const u16* Bp1 = Wt + (size_t)(bx*128 + (c1 >> 2))*2048 + (c1 & 3)*8;
  const u16* BsW0 = &Bs[(wv*64)*8];
  const u16* BsW1 = &Bs[(256 + wv*64)*8];

  const f32x4 fz = {0.f,0.f,0.f,0.f};
  f32x4 acc[4][4];
#pragma unroll
  for (int i=0;i<4;i++)
#pragma unroll
    for (int j=0;j<4;j++) acc[i][j] = fz;

  for (int kt = 0; kt < 64; ++kt){
    float4 a0 = *(const float4*)(Ap);
    float4 a1 = *(const float4*)(Ap + 4);
    float4 a2 = *(const float4*)(Ap + 8);
    float4 a3 = *(const float4*)(Ap + 12);
    Ap += 32;
    __syncthreads();
    uint4 w0, w1;
    w0.x = pk2(a0.x,a0.y); w0.y = pk2(a0.z,a0.w);
    w0.z = pk2(a1.x,a1.y); w0.w = pk2(a1.z,a1.w);
    w1.x = pk2(a2.x,a2.y); w1.y = pk2(a2.z,a2.w);
    w1.z = pk2(a3.x,a3.y); w1.w = pk2(a3.z,a3.w);
    *(uint4*)(AsW) = w0; *(uint4*)(AsW + 8) = w1;
    glds16(Bp0, BsW0);
    glds16(Bp1, BsW1);
    Bp0 += 32; Bp1 += 32;
    __syncthreads();
    bf16x8 af[4], bf[4];
#pragma unroll
    for (int i=0;i<4;i++) af[i] = ldfrag(&As[(wm*64 + i*16 + ln)*32 + lq*8]);
#pragma unroll
    for (int j=0;j<4;j++) bf[j] = ldfrag(&Bs[(wn*64 + j*16 + ln)*32 + lq*8]);
#pragma unroll
    for (int i=0;i<4;i++)
#pragma unroll
      for (int j=0;j<4;j++)
        acc[i][j] = __builtin_amdgcn_mfma_f32_16x16x32_bf16(af[i], bf[j], acc[i][j], 0,0,0);
  }
  qkv_epilogue(acc, bias, bx, by, wm, wn, lq, ln, qb, kb, vb);
}

// ---------------- proj GEMM: A = y bf16 head-major [BH][T][HD] (glds);
// B = Wpt^T bf16 [2048][2048] (glds); out fp32 [8192][2048].
__global__ __launch_bounds__(256,2) void gemm_proj(
    const u16* __restrict__ Y, const u16* __restrict__ Wt, const float* __restrict__ bias,
    float* __restrict__ outp)
{
  __shared__ u16 As[128*32];
  __shared__ u16 Bs[128*32];
  const int t = threadIdx.x;
  const int bx = blockIdx.x, by = blockIdx.y;
  const int lane = t & 63, wv = t >> 6;
  const int lq = lane >> 4, ln = lane & 15;
  const int wm = wv >> 1, wn = wv & 1;

  const int c0 = t, c1 = 256 + t;
  const int rA0 = by*128 + (c0 >> 2), rA1 = by*128 + (c1 >> 2);
  const u16* Ya0 = Y + ((size_t)((rA0 >> 10)*NH)*T_ + (rA0 & 1023))*HD;
  const u16* Ya1 = Y + ((size_t)((rA1 >> 10)*NH)*T_ + (rA1 & 1023))*HD;
  const int kc0 = (c0 & 3)*8, kc1 = (c1 & 3)*8;
  const u16* AsW0 = &As[(wv*64)*8];
  const u16* AsW1 = &As[(256 + wv*64)*8];

  const u16* Bp0 = Wt + (size_t)(bx*128 + (c0 >> 2))*2048 + (c0 & 3)*8;
  const u16* Bp1 = Wt + (size_t)(bx*128 + (c1 >> 2))*2048 + (c1 & 3)*8;
  const u16* BsW0 = &Bs[(wv*64)*8];
  const u16* BsW1 = &Bs[(256 + wv*64)*8];

  const f32x4 fz = {0.f,0.f,0.f,0.f};
  f32x4 acc[4][4];
#pragma unroll
  for (int i=0;i<4;i++)
#pragma unroll
    for (int j=0;j<4;j++) acc[i][j] = fz;

  for (int kt = 0; kt < 64; ++kt){
    __syncthreads();
    {
      const int k0 = kt*32 + kc0, k1 = kt*32 + kc1;    // head = k>>7, d = k&127
      glds16(Ya0 + (size_t)(k0 >> 7)*(T_*HD) + (k0 & 127), AsW0);
      glds16(Ya1 + (size_t)(k1 >> 7)*(T_*HD) + (k1 & 127), AsW1);
      glds16(Bp0, BsW0);
      glds16(Bp1, BsW1);
      Bp0 += 32; Bp1 += 32;
    }
    __syncthreads();
    bf16x8 af[4], bf[4];
#pragma unroll
    for (int i=0;i<4;i++) af[i] = ldfrag(&As[(wm*64 + i*16 + ln)*32 + lq*8]);
#pragma unroll
    for (int j=0;j<4;j++) bf[j] = ldfrag(&Bs[(wn*64 + j*16 + ln)*32 + lq*8]);
#pragma unroll
    for (int i=0;i<4;i++)
#pragma unroll
      for (int j=0;j<4;j++)
        acc[i][j] = __builtin_amdgcn_mfma_f32_16x16x32_bf16(af[i], bf[j], acc[i][j], 0,0,0);
  }

  float* op = outp + (size_t)(by*128)*2048 + bx*128;
#pragma unroll
  for (int j=0;j<4;j++){
    const float bv = bias[bx*128 + wn*64 + j*16 + ln];
    const int n = wn*64 + j*16 + ln;
#pragma unroll
    for (int i=0;i<4;i++){
      const int m0 = wm*64 + i*16 + lq*4;
#pragma unroll
      for (int r=0;r<4;r++)
        op[(size_t)(m0 + r)*2048 + n] = acc[i][j][r] + bv;
    }
  }
}

// ---------------- flash attention (unchanged from R8) -----------------------
__global__ __launch_bounds__(256,2) void attn_fwd(
    u16* qy, const u16* __restrict__ kk, const u16* __restrict__ vv)
{
  __shared__ u16 Ks[64*128];                   // [key][d], swizzled
  __shared__ u16 Vt[128*64];                   // [d][key], swizzled
  __shared__ u16 Ps[4*32*64];                  // per-wave P strip, swizzled
  const int qt = 7 - blockIdx.x, bh = blockIdx.y;
  const int t = threadIdx.x;
  const int lane = t & 63, wv = t >> 6;
  const int lq = lane >> 4, ln = lane & 15;

  bf16x8 qf[2][4];                             // A-frag: m=lane&15, k=quad*8+j
#pragma unroll
  for (int i=0;i<2;i++)
#pragma unroll
    for (int kc=0;kc<4;kc++){
      int qrow = qt*128 + wv*32 + i*16 + ln;
      qf[i][kc] = ldfrag(&qy[((size_t)bh*T_ + qrow)*HD + kc*32 + lq*8]);
    }

  const f32x4 fz = {0.f,0.f,0.f,0.f};
  f32x4 o[2][8];
#pragma unroll
  for (int i=0;i<2;i++)
#pragma unroll
    for (int jd=0;jd<8;jd++) o[i][jd] = fz;
  float mi[2][4], li[2][4];
#pragma unroll
  for (int i=0;i<2;i++)
#pragma unroll
    for (int r=0;r<4;r++){ mi[i][r] = -1e30f; li[i][r] = 0.f; }

  const float scale = 0.08838834764831843f;    // 1/sqrt(128)
  const int kr = t & 63, dbase = (t >> 6)*32;  // V-transpose stage mapping
  const int nkt = 2*qt + 2;                    // causal: keys < (qt+1)*128

  uint4 kreg[4];
  uint4 vreg[4];
  {
    const uint4* ksrc = (const uint4*)(kk + (size_t)bh*T_*HD);
#pragma unroll
    for (int ii=0; ii<4; ++ii) kreg[ii] = ksrc[t + ii*256];
#pragma unroll
    for (int ch=0; ch<4; ++ch)
      vreg[ch] = *(const uint4*)&vv[((size_t)bh*T_ + kr)*HD + dbase + ch*8];
  }

  for (int kt = 0; kt < nkt; ++kt){
    __syncthreads();                           // prior iter done reading Ks/Vt
    uint4* kdst = (uint4*)Ks;
#pragma unroll
    for (int ii=0; ii<4; ++ii){
      const int c = t + ii*256;                // chunk: row c>>4, slot c&15
      kdst[(c & ~15) | ((c & 15) ^ ((c >> 4) & 7))] = kreg[ii];
    }
#pragma unroll
    for (int ch=0; ch<4; ++ch){
      const u16* e = (const u16*)&vreg[ch];
#pragma unroll
      for (int j=0; j<8; ++j){
        const int d = dbase + ch*8 + j;
        Vt[d*64 + (kr ^ ((d & 7) << 3))] = e[j]; // distinct cols/lane: free
      }
    }
    __syncthreads();

    {
      const int ktn = (kt+1 < nkt) ? kt+1 : kt;   // last iter: harmless reload
      const uint4* ksrc = (const uint4*)(kk + ((size_t)bh*T_ + ktn*64)*HD);
#pragma unroll
      for (int ii=0; ii<4; ++ii) kreg[ii] = ksrc[t + ii*256];
#pragma unroll
      for (int ch=0; ch<4; ++ch)
        vreg[ch] = *(const uint4*)&vv[((size_t)bh*T_ + ktn*64 + kr)*HD + dbase + ch*8];
    }

    // S = Q K^T
    f32x4 s[2][4];
#pragma unroll
    for (int i=0;i<2;i++)
#pragma unroll
      for (int j=0;j<4;j++) s[i][j] = fz;
    __builtin_amdgcn_s_setprio(1);
#pragma unroll
    for (int j=0;j<4;j++){
      bf16x8 kf[4];                            // B-frag: n=key, k=d
      const int krow = j*16 + ln;
      const int ksw = (krow & 7) << 3;
#pragma unroll
      for (int kc=0;kc<4;kc++)
        kf[kc] = ldfrag(&Ks[krow*128 + ((kc*32 + lq*8) ^ ksw)]);
#pragma unroll
      for (int i=0;i<2;i++)
#pragma unroll
        for (int kc=0;kc<4;kc++)
          s[i][j] = __builtin_amdgcn_mfma_f32_16x16x32_bf16(qf[i][kc], kf[kc], s[i][j], 0,0,0);
    }
    __builtin_amdgcn_s_setprio(0);

    // scale + causal mask (C/D: row=quad*4+r, col=lane&15)
#pragma unroll
    for (int i=0;i<2;i++)
#pragma unroll
      for (int j=0;j<4;j++)
#pragma unroll
        for (int r=0;r<4;r++){
          int qg = qt*128 + wv*32 + i*16 + lq*4 + r;
          int kg = kt*64 + j*16 + ln;
          float sv = s[i][j][r]*scale;
          s[i][j][r] = (kg > qg) ? -1e30f : sv;
        }

    // online softmax with defer-max (THR=8)
    float mxv[2][4];
#pragma unroll
    for (int i=0;i<2;i++)
#pragma unroll
      for (int r=0;r<4;r++){
        float mx = fmaxf(fmaxf(s[i][0][r], s[i][1][r]), fmaxf(s[i][2][r], s[i][3][r]));
        mx = fmaxf(mx, __shfl_xor(mx, 1));
        mx = fmaxf(mx, __shfl_xor(mx, 2));
        mx = fmaxf(mx, __shfl_xor(mx, 4));
        mx = fmaxf(mx, __shfl_xor(mx, 8));
        mxv[i][r] = mx;
      }
    bool ok = true;
#pragma unroll
    for (int i=0;i<2;i++)
#pragma unroll
      for (int r=0;r<4;r++) ok = ok && (mxv[i][r] <= mi[i][r] + 8.0f);
    if (!__all((int)ok)){
#pragma unroll
      for (int i=0;i<2;i++)
#pragma unroll
        for (int r=0;r<4;r++){
          float mnew = fmaxf(mi[i][r], mxv[i][r]);
          float alpha = __expf(mi[i][r] - mnew);
          li[i][r] *= alpha;
          mi[i][r] = mnew;
#pragma unroll
          for (int jd=0;jd<8;jd++) o[i][jd][r] *= alpha;
        }
    }
#pragma unroll
    for (int i=0;i<2;i++)
#pragma unroll
      for (int r=0;r<4;r++){
        float rs = 0.f;
#pragma unroll
        for (int j=0;j<4;j++){
          float p = __expf(s[i][j][r] - mi[i][r]);   // bounded by e^8
          s[i][j][r] = p; rs += p;
        }
        rs += __shfl_xor(rs, 1); rs += __shfl_xor(rs, 2);
        rs += __shfl_xor(rs, 4); rs += __shfl_xor(rs, 8);
        li[i][r] += rs;
      }

    // P: C-layout -> per-wave LDS strip (swizzled) -> A-layout frags
#pragma unroll
    for (int i=0;i<2;i++)
#pragma unroll
      for (int j=0;j<4;j++)
#pragma unroll
        for (int r=0;r<4;r++){
          const int rr = i*16 + lq*4 + r;
          Ps[wv*2048 + rr*64 + ((j*16 + ln) ^ ((rr & 7) << 3))] = f2b(s[i][j][r]);
        }

    bf16x8 pf[2][2];
#pragma unroll
    for (int i=0;i<2;i++){
      const int prow = i*16 + ln;
      const int psw = (prow & 7) << 3;
#pragma unroll
      for (int kc=0;kc<2;kc++)
        pf[i][kc] = ldfrag(&Ps[wv*2048 + prow*64 + ((kc*32 + lq*8) ^ psw)]);
    }
    __builtin_amdgcn_s_setprio(1);
#pragma unroll
    for (int jd=0;jd<8;jd++){
      const int vrow = jd*16 + ln;
      const int vsw = (vrow & 7) << 3;
#pragma unroll
      for (int kc=0;kc<2;kc++){
        bf16x8 vf = ldfrag(&Vt[vrow*64 + ((kc*32 + lq*8) ^ vsw)]);
#pragma unroll
        for (int i=0;i<2;i++)
          o[i][jd] = __builtin_amdgcn_mfma_f32_16x16x32_bf16(pf[i][kc], vf, o[i][jd], 0,0,0);
      }
    }
    __builtin_amdgcn_s_setprio(0);
  }

  // epilogue: y over own Q tile, head-major [BH][T][HD]
#pragma unroll
  for (int i=0;i<2;i++)
#pragma unroll
    for (int r=0;r<4;r++){
      float inv = 1.f / li[i][r];
      int row = qt*128 + wv*32 + i*16 + lq*4 + r;
#pragma unroll
      for (int jd=0;jd<8;jd++)
        qy[((size_t)bh*T_ + row)*HD + jd*16 + ln] = f2b(o[i][jd][r] * inv);
    }
}

extern "C" void kernel_launch(void* const* d_in, const int* in_sizes, int n_in,
                              void* d_out, int out_size, void* d_ws, size_t ws_size,
                              hipStream_t stream)
{
  const float* x      = (const float*)d_in[0];   // [8192][2048] fp32
  const float* W_attn = (const float*)d_in[1];   // [2048][6144] fp32
  const float* b_attn = (const float*)d_in[2];   // [6144] fp32
  const float* W_proj = (const float*)d_in[3];   // [2048][2048] fp32
  const float* b_proj = (const float*)d_in[4];   // [2048] fp32
  float* out = (float*)d_out;                    // [8192][2048] fp32

  u16* Wat = (u16*)d_ws;                         // [6144][2048] bf16 = W_attn^T
  u16* Wpt = Wat + (size_t)6144*2048;            // [2048][2048] bf16 = W_proj^T
  u16* qb  = Wpt + (size_t)2048*2048;            // Q bf16, then y bf16
  u16* xb  = qb  + (size_t)BH*T_*HD;             // x bf16 (only if ws >= 96 MiB)
  u16* kb  = (u16*)d_out;                        // K bf16 (d_out low half)
  u16* vb  = kb + (size_t)BH*T_*HD;              // V bf16 (d_out high half)

  const size_t need = ((size_t)6144*2048 + (size_t)2048*2048
                       + 2*(size_t)BH*T_*HD) * sizeof(u16);   // 96 MiB

  hipLaunchKernelGGL(transpose_cvt, dim3(96,32,1), dim3(256,1,1), 0, stream,
                     W_attn, Wat, 2048, 6144);
  hipLaunchKernelGGL(transpose_cvt, dim3(32,32,1), dim3(256,1,1), 0, stream,
                     W_proj, Wpt, 2048, 2048);
  if (ws_size >= need){
    hipLaunchKernelGGL(cvt_bf16, dim3(1024,1,1), dim3(256,1,1), 0, stream,
                       (const float4*)x, (ushort4*)xb, (B_*T_*C_)/4);
    hipLaunchKernelGGL(gemm_qkv_8p, dim3(768,1,1), dim3(512,1,1), 0, stream,
                       xb, Wat, b_attn, qb, kb, vb);
  } else {
    hipLaunchKernelGGL(gemm_qkv_f32, dim3(48,64,1), dim3(256,1,1), 0, stream,
                       x, Wat, b_attn, qb, kb, vb);
  }
  hipLaunchKernelGGL(attn_fwd, dim3(8,BH,1), dim3(256,1,1), 0, stream,
                     qb, kb, vb);
  hipLaunchKernelGGL(gemm_proj, dim3(16,64,1), dim3(256,1,1), 0, stream,
                     qb, Wpt, b_proj, out);
}

// Round 5
// 605.702 us; speedup vs baseline: 1.0686x; 1.0365x over previous
//
#include <hip/hip_runtime.h>
#include <hip/hip_bf16.h>

// CausalSelfAttention: B=8 T=1024 C=2048 NH=16 HD=128. FP32 I/O, bf16 MFMA.
// R10: proj GEMM ported to the R9-proven 256x256 8-phase counted-vmcnt
// template (gemm_proj_8p): same schedule/proof, A = y head-major (k-chunk
// 64-aligned -> single head per STAGE), fp32 epilogue. attn: waves fully
// causal-masked on a k-tile skip compute (wave-uniform). qkv_8p unchanged
// (932 TF; read-rebalance rejected: loses the lgkm-drain-before-stage
// safety invariant).
// ws: Wat^T 24M | Wpt^T 8M | Q 32M (y overwrites Q after attn) | [xb 32M].
// d_out: K bf16 | V bf16 until proj GEMM overwrites with fp32 result.

typedef unsigned short u16;
typedef __bf16 bf16x8 __attribute__((ext_vector_type(8)));
typedef float f32x4 __attribute__((ext_vector_type(4)));

#define B_ 8
#define T_ 1024
#define C_ 2048
#define NH 16
#define HD 128
#define BH (B_*NH)

__device__ __forceinline__ u16 f2b(float f){
  __bf16 h = (__bf16)f; return __builtin_bit_cast(u16, h);   // RNE
}
__device__ __forceinline__ unsigned pk2(float x, float y){
  return (unsigned)f2b(x) | ((unsigned)f2b(y) << 16);
}
__device__ __forceinline__ bf16x8 ldfrag(const u16* p){
  uint4 u = *(const uint4*)p; return __builtin_bit_cast(bf16x8, u);
}
__device__ __forceinline__ void glds16(const u16* g, const u16* l){
  __builtin_amdgcn_global_load_lds(
      (const __attribute__((address_space(1))) void*)g,
      (__attribute__((address_space(3))) void*)l, 16, 0, 0);
}
__device__ __forceinline__ void sbar(){
  __builtin_amdgcn_sched_barrier(0);
  __builtin_amdgcn_s_barrier();
  __builtin_amdgcn_sched_barrier(0);
}

// ---------------- fp32 -> bf16 pack, n4 = n/4 ------------------------------
__global__ __launch_bounds__(256) void cvt_bf16(
    const float4* __restrict__ in, ushort4* __restrict__ outp, int n4)
{
  int i = blockIdx.x*256 + threadIdx.x;
  const int stride = gridDim.x*256;
  for (; i < n4; i += stride){
    float4 f = in[i];
    ushort4 o; o.x = f2b(f.x); o.y = f2b(f.y); o.z = f2b(f.z); o.w = f2b(f.w);
    outp[i] = o;
  }
}

// ---------------- W fp32 [R][C] -> bf16 W^T [C][R], 64x64 tiles --------------
__global__ __launch_bounds__(256) void transpose_cvt(
    const float* __restrict__ in, u16* __restrict__ outp, int R, int C)
{
  __shared__ u16 tile[64][65];
  const int t = threadIdx.x;
  const int r0 = blockIdx.y * 64, c0 = blockIdx.x * 64;
#pragma unroll
  for (int ii = 0; ii < 16; ++ii){
    int idx = t + ii*256; int r = idx >> 6, c = idx & 63;
    tile[r][c] = f2b(in[(size_t)(r0 + r)*C + c0 + c]);
  }
  __syncthreads();
#pragma unroll
  for (int ii = 0; ii < 16; ++ii){
    int idx = t + ii*256; int r = idx >> 6, c = idx & 63;
    outp[(size_t)(c0 + r)*R + r0 + c] = tile[c][r];
  }
}

// ---------------- QKV epilogue for 128-tile fallback path -------------------
__device__ __forceinline__ void qkv_epilogue(
    const f32x4 acc[4][4], const float* bias, int bx, int by,
    int wm, int wn, int lq, int ln,
    u16* qb, u16* kb, u16* vb)
{
  const int tensor = bx >> 4, h = bx & 15, b = by >> 3, t0 = (by & 7)*128;
  u16* tb = tensor==0 ? qb : (tensor==1 ? kb : vb);
  u16* op = tb + ((size_t)(b*NH + h)*T_ + t0)*HD;
#pragma unroll
  for (int j=0;j<4;j++){
    const float bv = bias[bx*128 + wn*64 + j*16 + ln];
    const int n = wn*64 + j*16 + ln;
#pragma unroll
    for (int i=0;i<4;i++){
      const int m0 = wm*64 + i*16 + lq*4;      // C/D: row = quad*4 + reg
#pragma unroll
      for (int r=0;r<4;r++)
        op[(size_t)(m0 + r)*HD + n] = f2b(acc[i][j][r] + bv);
    }
  }
}

// ---------------- QKV GEMM, 256x256 8-phase (R9, unchanged) -----------------
__global__ __launch_bounds__(512,2) void gemm_qkv_8p(
    const u16* __restrict__ Xb, const u16* __restrict__ Wt,
    const float* __restrict__ bias,
    u16* __restrict__ qb, u16* __restrict__ kb, u16* __restrict__ vb)
{
  __shared__ u16 lds[2][2][256*64];            // [buf][A/B][row][k] 128 KiB
  const int t = threadIdx.x;                   // 0..511
  const int lane = t & 63, wid = t >> 6;       // 8 waves: 2M x 4N
  const int lq = lane >> 4, ln = lane & 15;
  const int wm = wid >> 2, wn = wid & 3;

  // XCD-aware swizzle (768 blocks, 768%8==0 -> simple form is bijective)
  const int bid0 = blockIdx.x;
  const int bid = (bid0 & 7)*96 + (bid0 >> 3);
  const int bx = bid % 24, by = bid / 24;      // bx: N/256, by: M/256

  const int rl  = (wid << 4) + (lane >> 3);    // q=0 local row (0..127)
  const int sw0 = (lane & 7) ^ (rl & 7);
  const u16* Ag = Xb + ((size_t)(by*256) + rl)*2048;
  const u16* Bg = Wt + ((size_t)(bx*256) + rl)*2048;
  const size_t q0off = (size_t)sw0*8;
  const size_t q1off = (size_t)8*2048 + (size_t)sw0*8;   // (rl+8)&7 == rl&7

#define STAGE(buf_, op_, h_, T_) do { \
    const u16* s_ = (op_ ? Bg : Ag) + (size_t)(h_)*(128*2048) + (size_t)(T_)*64; \
    const u16* d_ = &lds[buf_][op_][(((h_)*128) + (wid<<4))*64]; \
    glds16(s_ + q0off, d_); \
    glds16(s_ + q1off, d_ + 8*64); \
  } while(0)

  const int swr0 = (0*4 + lq) ^ (ln & 7);
  const int swr1 = (1*4 + lq) ^ (ln & 7);

  const f32x4 fz = {0.f,0.f,0.f,0.f};
  f32x4 acc[8][4];
#pragma unroll
  for (int f=0;f<8;f++)
#pragma unroll
    for (int g=0;g<4;g++) acc[f][g] = fz;

  // prologue: tile0 fully + tile1's Bhi,Blo,Ahi (Alo(1) comes at (0,+0))
  STAGE(0,0,0,0); STAGE(0,0,1,0); STAGE(0,1,0,0); STAGE(0,1,1,0);
  STAGE(1,1,0,1); STAGE(1,1,1,1); STAGE(1,0,0,1);
  asm volatile("s_waitcnt vmcnt(6)" ::: "memory");   // tile0 landed
  sbar();

  for (int T = 0; T < 32; ++T){
    const int b = T & 1;
    const u16* As = lds[b][0];
    const u16* Bs = lds[b][1];
    bf16x8 a0[4][2], a4[4][2], bfr[4][2];

    // ---- phase +0: read A frags 0-3 + all B frags; stage Alo(T+1)
#pragma unroll
    for (int f=0;f<4;f++){
      a0[f][0]  = ldfrag(&As[(wm*128 + f*16 + ln)*64 + swr0*8]);
      a0[f][1]  = ldfrag(&As[(wm*128 + f*16 + ln)*64 + swr1*8]);
      bfr[f][0] = ldfrag(&Bs[(wn*64  + f*16 + ln)*64 + swr0*8]);
      bfr[f][1] = ldfrag(&Bs[(wn*64  + f*16 + ln)*64 + swr1*8]);
    }
    if (T+1 < 32) STAGE(b^1, 0, 1, T+1);
    sbar();
    __builtin_amdgcn_s_setprio(1);
#pragma unroll
    for (int f=0;f<4;f++)
#pragma unroll
      for (int g=0;g<2;g++){
        acc[f][g] = __builtin_amdgcn_mfma_f32_16x16x32_bf16(a0[f][0], bfr[g][0], acc[f][g], 0,0,0);
        acc[f][g] = __builtin_amdgcn_mfma_f32_16x16x32_bf16(a0[f][1], bfr[g][1], acc[f][g], 0,0,0);
      }
    __builtin_amdgcn_s_setprio(0);
    sbar();

    // ---- phase +1: read A frags 4-7; stage Bhi(T+2)
#pragma unroll
    for (int f=0;f<4;f++){
      a4[f][0] = ldfrag(&As[(wm*128 + (f+4)*16 + ln)*64 + swr0*8]);
      a4[f][1] = ldfrag(&As[(wm*128 + (f+4)*16 + ln)*64 + swr1*8]);
    }
    if (T+2 < 32) STAGE(b, 1, 0, T+2);
    sbar();
    __builtin_amdgcn_s_setprio(1);
#pragma unroll
    for (int f=0;f<4;f++)
#pragma unroll
      for (int g=0;g<2;g++){
        acc[f+4][g] = __builtin_amdgcn_mfma_f32_16x16x32_bf16(a4[f][0], bfr[g][0], acc[f+4][g], 0,0,0);
        acc[f+4][g] = __builtin_amdgcn_mfma_f32_16x16x32_bf16(a4[f][1], bfr[g][1], acc[f+4][g], 0,0,0);
      }
    __builtin_amdgcn_s_setprio(0);
    sbar();

    // ---- phase +2: no reads; stage Blo(T+2)
    if (T+2 < 32) STAGE(b, 1, 1, T+2);
    sbar();
    __builtin_amdgcn_s_setprio(1);
#pragma unroll
    for (int f=0;f<4;f++)
#pragma unroll
      for (int g=2;g<4;g++){
        acc[f+4][g] = __builtin_amdgcn_mfma_f32_16x16x32_bf16(a4[f][0], bfr[g][0], acc[f+4][g], 0,0,0);
        acc[f+4][g] = __builtin_amdgcn_mfma_f32_16x16x32_bf16(a4[f][1], bfr[g][1], acc[f+4][g], 0,0,0);
      }
    __builtin_amdgcn_s_setprio(0);
    sbar();

    // ---- phase +3: no reads; stage Ahi(T+2); counted vmcnt
    if (T+2 < 32) STAGE(b, 0, 0, T+2);
    if (T >= 30) asm volatile("s_waitcnt vmcnt(0)" ::: "memory");
    else         asm volatile("s_waitcnt vmcnt(6)" ::: "memory");
    sbar();
    __builtin_amdgcn_s_setprio(1);
#pragma unroll
    for (int f=0;f<4;f++)
#pragma unroll
      for (int g=2;g<4;g++){
        acc[f][g] = __builtin_amdgcn_mfma_f32_16x16x32_bf16(a0[f][0], bfr[g][0], acc[f][g], 0,0,0);
        acc[f][g] = __builtin_amdgcn_mfma_f32_16x16x32_bf16(a0[f][1], bfr[g][1], acc[f][g], 0,0,0);
      }
    __builtin_amdgcn_s_setprio(0);
    sbar();
  }
#undef STAGE

  // epilogue: scatter to Q/K/V [BH][T][HD]
  const int tensor = bx >> 3;
  u16* tb = tensor==0 ? qb : (tensor==1 ? kb : vb);
  const int m_base = by*256 + wm*128;
#pragma unroll
  for (int g=0; g<4; ++g){
    const int ncol = (bx & 7)*256 + wn*64 + g*16 + ln;   // 0..2047 in tensor
    const float bv = bias[tensor*2048 + ncol];
    const int h = ncol >> 7, d = ncol & 127;
#pragma unroll
    for (int f=0; f<8; ++f){
      const int m0 = m_base + f*16 + lq*4;
      const int bb = m0 >> 10, tt = m0 & 1023;           // rows m0..m0+3 same b
      u16* op = tb + ((size_t)(bb*NH + h)*T_ + tt)*HD + d;
#pragma unroll
      for (int r=0;r<4;++r)
        op[(size_t)r*HD] = f2b(acc[f][g][r] + bv);
    }
  }
}

// ---------------- proj GEMM, R10: 256x256 8-phase, A = y head-major ---------
// A row m = by*256 + h_*128 + rl -> batch b=by>>2, t=(by&3)*256+h_*128+rl.
// K-chunk T*64+[0,64) sits in head T>>1, d=(T&1)*64+slot*8 (64 | 128).
__global__ __launch_bounds__(512,2) void gemm_proj_8p(
    const u16* __restrict__ Y, const u16* __restrict__ Wt,
    const float* __restrict__ bias, float* __restrict__ outp)
{
  __shared__ u16 lds[2][2][256*64];            // [buf][A/B][row][k] 128 KiB
  const int t = threadIdx.x;
  const int lane = t & 63, wid = t >> 6;
  const int lq = lane >> 4, ln = lane & 15;
  const int wm = wid >> 2, wn = wid & 3;

  // 256 blocks, 256%8==0 -> bijective XCD swizzle
  const int bid0 = blockIdx.x;
  const int bid = (bid0 & 7)*32 + (bid0 >> 3);
  const int bx = bid & 7, by = bid >> 3;       // bx: N/256 (8), by: M/256 (32)

  const int rl  = (wid << 4) + (lane >> 3);
  const int sw0 = (lane & 7) ^ (rl & 7);
  const u16* Bg = Wt + ((size_t)(bx*256) + rl)*2048;
  const size_t bq0 = (size_t)sw0*8;
  // A base: everything except the per-(h_,T) head/d terms
  const size_t arow0 = ((size_t)(by >> 2)*16)*1024 + (size_t)(by & 3)*256 + rl;

#define STAGEP(buf_, op_, h_, Tt_) do { \
    const u16* d_ = &lds[buf_][op_][(((h_)*128) + (wid<<4))*64]; \
    if (op_){ \
      const u16* s_ = Bg + (size_t)(h_)*(128*2048) + (size_t)(Tt_)*64; \
      glds16(s_ + bq0, d_); \
      glds16(s_ + (size_t)8*2048 + bq0, d_ + 8*64); \
    } else { \
      const u16* s_ = Y + (arow0 + (size_t)((Tt_) >> 1)*1024 + (size_t)(h_)*128)*128 \
                        + ((Tt_) & 1)*64 + sw0*8; \
      glds16(s_, d_); \
      glds16(s_ + 8*128, d_ + 8*64); \
    } \
  } while(0)

  const int swr0 = (0*4 + lq) ^ (ln & 7);
  const int swr1 = (1*4 + lq) ^ (ln & 7);

  const f32x4 fz = {0.f,0.f,0.f,0.f};
  f32x4 acc[8][4];
#pragma unroll
  for (int f=0;f<8;f++)
#pragma unroll
    for (int g=0;g<4;g++) acc[f][g] = fz;

  STAGEP(0,0,0,0); STAGEP(0,0,1,0); STAGEP(0,1,0,0); STAGEP(0,1,1,0);
  STAGEP(1,1,0,1); STAGEP(1,1,1,1); STAGEP(1,0,0,1);
  asm volatile("s_waitcnt vmcnt(6)" ::: "memory");
  sbar();

  for (int T = 0; T < 32; ++T){
    const int b = T & 1;
    const u16* As = lds[b][0];
    const u16* Bs = lds[b][1];
    bf16x8 a0[4][2], a4[4][2], bfr[4][2];

#pragma unroll
    for (int f=0;f<4;f++){
      a0[f][0]  = ldfrag(&As[(wm*128 + f*16 + ln)*64 + swr0*8]);
      a0[f][1]  = ldfrag(&As[(wm*128 + f*16 + ln)*64 + swr1*8]);
      bfr[f][0] = ldfrag(&Bs[(wn*64  + f*16 + ln)*64 + swr0*8]);
      bfr[f][1] = ldfrag(&Bs[(wn*64  + f*16 + ln)*64 + swr1*8]);
    }
    if (T+1 < 32) STAGEP(b^1, 0, 1, T+1);
    sbar();
    __builtin_amdgcn_s_setprio(1);
#pragma unroll
    for (int f=0;f<4;f++)
#pragma unroll
      for (int g=0;g<2;g++){
        acc[f][g] = __builtin_amdgcn_mfma_f32_16x16x32_bf16(a0[f][0], bfr[g][0], acc[f][g], 0,0,0);
        acc[f][g] = __builtin_amdgcn_mfma_f32_16x16x32_bf16(a0[f][1], bfr[g][1], acc[f][g], 0,0,0);
      }
    __builtin_amdgcn_s_setprio(0);
    sbar();

#pragma unroll
    for (int f=0;f<4;f++){
      a4[f][0] = ldfrag(&As[(wm*128 + (f+4)*16 + ln)*64 + swr0*8]);
      a4[f][1] = ldfrag(&As[(wm*128 + (f+4)*16 + ln)*64 + swr1*8]);
    }
    if (T+2 < 32) STAGEP(b, 1, 0, T+2);
    sbar();
    __builtin_amdgcn_s_setprio(1);
#pragma unroll
    for (int f=0;f<4;f++)
#pragma unroll
      for (int g=0;g<2;g++){
        acc[f+4][g] = __builtin_amdgcn_mfma_f32_16x16x32_bf16(a4[f][0], bfr[g][0], acc[f+4][g], 0,0,0);
        acc[f+4][g] = __builtin_amdgcn_mfma_f32_16x16x32_bf16(a4[f][1], bfr[g][1], acc[f+4][g], 0,0,0);
      }
    __builtin_amdgcn_s_setprio(0);
    sbar();

    if (T+2 < 32) STAGEP(b, 1, 1, T+2);
    sbar();
    __builtin_amdgcn_s_setprio(1);
#pragma unroll
    for (int f=0;f<4;f++)
#pragma unroll
      for (int g=2;g<4;g++){
        acc[f+4][g] = __builtin_amdgcn_mfma_f32_16x16x32_bf16(a4[f][0], bfr[g][0], acc[f+4][g], 0,0,0);
        acc[f+4][g] = __builtin_amdgcn_mfma_f32_16x16x32_bf16(a4[f][1], bfr[g][1], acc[f+4][g], 0,0,0);
      }
    __builtin_amdgcn_s_setprio(0);
    sbar();

    if (T+2 < 32) STAGEP(b, 0, 0, T+2);
    if (T >= 30) asm volatile("s_waitcnt vmcnt(0)" ::: "memory");
    else         asm volatile("s_waitcnt vmcnt(6)" ::: "memory");
    sbar();
    __builtin_amdgcn_s_setprio(1);
#pragma unroll
    for (int f=0;f<4;f++)
#pragma unroll
      for (int g=2;g<4;g++){
        acc[f][g] = __builtin_amdgcn_mfma_f32_16x16x32_bf16(a0[f][0], bfr[g][0], acc[f][g], 0,0,0);
        acc[f][g] = __builtin_amdgcn_mfma_f32_16x16x32_bf16(a0[f][1], bfr[g][1], acc[f][g], 0,0,0);
      }
    __builtin_amdgcn_s_setprio(0);
    sbar();
  }
#undef STAGEP

  // epilogue: fp32 out [8192][2048]
  const int m_base = by*256 + wm*128;
#pragma unroll
  for (int g=0; g<4; ++g){
    const int ncol = bx*256 + wn*64 + g*16 + ln;
    const float bv = bias[ncol];
#pragma unroll
    for (int f=0; f<8; ++f){
      const int m0 = m_base + f*16 + lq*4;
      float* op = outp + (size_t)m0*2048 + ncol;
#pragma unroll
      for (int r=0;r<4;++r)
        op[(size_t)r*2048] = acc[f][g][r] + bv;
    }
  }
}

// ---------------- QKV GEMM, fallback: A = x fp32 (cvt in staging). ----------
__global__ __launch_bounds__(256,2) void gemm_qkv_f32(
    const float* __restrict__ X, const u16* __restrict__ Wt, const float* __restrict__ bias,
    u16* __restrict__ qb, u16* __restrict__ kb, u16* __restrict__ vb)
{
  __shared__ u16 As[128*32];
  __shared__ u16 Bs[128*32];
  const int t = threadIdx.x;
  const int bx = blockIdx.x, by = blockIdx.y;
  const int lane = t & 63, wv = t >> 6;
  const int lq = lane >> 4, ln = lane & 15;
  const int wm = wv >> 1, wn = wv & 1;

  const int ar = t >> 1, ah = t & 1;
  const float* Ap = X + (size_t)(by*128 + ar)*2048 + ah*16;
  u16* AsW = &As[ar*32 + ah*16];

  const int c0 = t, c1 = 256 + t;
  const u16* Bp0 = Wt + (size_t)(bx*128 + (c0 >> 2))*2048 + (c0 & 3)*8;
  const u16* Bp1 = Wt + (size_t)(bx*128 + (c1 >> 2))*2048 + (c1 & 3)*8;
  const u16* BsW0 = &Bs[(wv*64)*8];
  const u16* BsW1 = &Bs[(256 + wv*64)*8];

  const f32x4 fz = {0.f,0.f,0.f,0.f};
  f32x4 acc[4][4];
#pragma unroll
  for (int i=0;i<4;i++)
#pragma unroll
    for (int j=0;j<4;j++) acc[i][j] = fz;

  for (int kt = 0; kt < 64; ++kt){
    float4 a0 = *(const float4*)(Ap);
    float4 a1 = *(const float4*)(Ap + 4);
    float4 a2 = *(const float4*)(Ap + 8);
    float4 a3 = *(const float4*)(Ap + 12);
    Ap += 32;
    __syncthreads();
    uint4 w0, w1;
    w0.x = pk2(a0.x,a0.y); w0.y = pk2(a0.z,a0.w);
    w0.z = pk2(a1.x,a1.y); w0.w = pk2(a1.z,a1.w);
    w1.x = pk2(a2.x,a2.y); w1.y = pk2(a2.z,a2.w);
    w1.z = pk2(a3.x,a3.y); w1.w = pk2(a3.z,a3.w);
    *(uint4*)(AsW) = w0; *(uint4*)(AsW + 8) = w1;
    glds16(Bp0, BsW0);
    glds16(Bp1, BsW1);
    Bp0 += 32; Bp1 += 32;
    __syncthreads();
    bf16x8 af[4], bf[4];
#pragma unroll
    for (int i=0;i<4;i++) af[i] = ldfrag(&As[(wm*64 + i*16 + ln)*32 + lq*8]);
#pragma unroll
    for (int j=0;j<4;j++) bf[j] = ldfrag(&Bs[(wn*64 + j*16 + ln)*32 + lq*8]);
#pragma unroll
    for (int i=0;i<4;i++)
#pragma unroll
      for (int j=0;j<4;j++)
        acc[i][j] = __builtin_amdgcn_mfma_f32_16x16x32_bf16(af[i], bf[j], acc[i][j], 0,0,0);
  }
  qkv_epilogue(acc, bias, bx, by, wm, wn, lq, ln, qb, kb, vb);
}

// ---------------- flash attention (R9 + masked-tile wave skip) --------------
__global__ __launch_bounds__(256,2) void attn_fwd(
    u16* qy, const u16* __restrict__ kk, const u16* __restrict__ vv)
{
  __shared__ u16 Ks[64*128];                   // [key][d], swizzled
  __shared__ u16 Vt[128*64];                   // [d][key], swizzled
  __shared__ u16 Ps[4*32*64];                  // per-wave P strip, swizzled
  const int qt = 7 - blockIdx.x, bh = blockIdx.y;
  const int t = threadIdx.x;
  const int lane = t & 63, wv = t >> 6;
  const int lq = lane >> 4, ln = lane & 15;

  bf16x8 qf[2][4];                             // A-frag: m=lane&15, k=quad*8+j
#pragma unroll
  for (int i=0;i<2;i++)
#pragma unroll
    for (int kc=0;kc<4;kc++){
      int qrow = qt*128 + wv*32 + i*16 + ln;
      qf[i][kc] = ldfrag(&qy[((size_t)bh*T_ + qrow)*HD + kc*32 + lq*8]);
    }

  const f32x4 fz = {0.f,0.f,0.f,0.f};
  f32x4 o[2][8];
#pragma unroll
  for (int i=0;i<2;i++)
#pragma unroll
    for (int jd=0;jd<8;jd++) o[i][jd] = fz;
  float mi[2][4], li[2][4];
#pragma unroll
  for (int i=0;i<2;i++)
#pragma unroll
    for (int r=0;r<4;r++){ mi[i][r] = -1e30f; li[i][r] = 0.f; }

  const float scale = 0.08838834764831843f;    // 1/sqrt(128)
  const int kr = t & 63, dbase = (t >> 6)*32;  // V-transpose stage mapping
  const int nkt = 2*qt + 2;                    // causal: keys < (qt+1)*128

  uint4 kreg[4];
  uint4 vreg[4];
  {
    const uint4* ksrc = (const uint4*)(kk + (size_t)bh*T_*HD);
#pragma unroll
    for (int ii=0; ii<4; ++ii) kreg[ii] = ksrc[t + ii*256];
#pragma unroll
    for (int ch=0; ch<4; ++ch)
      vreg[ch] = *(const uint4*)&vv[((size_t)bh*T_ + kr)*HD + dbase + ch*8];
  }

  for (int kt = 0; kt < nkt; ++kt){
    __syncthreads();                           // prior iter done reading Ks/Vt
    uint4* kdst = (uint4*)Ks;
#pragma unroll
    for (int ii=0; ii<4; ++ii){
      const int c = t + ii*256;                // chunk: row c>>4, slot c&15
      kdst[(c & ~15) | ((c & 15) ^ ((c >> 4) & 7))] = kreg[ii];
    }
#pragma unroll
    for (int ch=0; ch<4; ++ch){
      const u16* e = (const u16*)&vreg[ch];
#pragma unroll
      for (int j=0; j<8; ++j){
        const int d = dbase + ch*8 + j;
        Vt[d*64 + (kr ^ ((d & 7) << 3))] = e[j]; // distinct cols/lane: free
      }
    }
    __syncthreads();

    {
      const int ktn = (kt+1 < nkt) ? kt+1 : kt;   // last iter: harmless reload
      const uint4* ksrc = (const uint4*)(kk + ((size_t)bh*T_ + ktn*64)*HD);
#pragma unroll
      for (int ii=0; ii<4; ++ii) kreg[ii] = ksrc[t + ii*256];
#pragma unroll
      for (int ch=0; ch<4; ++ch)
        vreg[ch] = *(const uint4*)&vv[((size_t)bh*T_ + ktn*64 + kr)*HD + dbase + ch*8];
    }

    // waves whose whole q-range is masked for this k-tile skip compute
    // (wave-uniform branch; barriers are all outside).
    const bool active = (kt*64) <= (qt*128 + wv*32 + 31);
    if (active){

    // S = Q K^T
    f32x4 s[2][4];
#pragma unroll
    for (int i=0;i<2;i++)
#pragma unroll
      for (int j=0;j<4;j++) s[i][j] = fz;
    __builtin_amdgcn_s_setprio(1);
#pragma unroll
    for (int j=0;j<4;j++){
      bf16x8 kf[4];                            // B-frag: n=key, k=d
      const int krow = j*16 + ln;
      const int ksw = (krow & 7) << 3;
#pragma unroll
      for (int kc=0;kc<4;kc++)
        kf[kc] = ldfrag(&Ks[krow*128 + ((kc*32 + lq*8) ^ ksw)]);
#pragma unroll
      for (int i=0;i<2;i++)
#pragma unroll
        for (int kc=0;kc<4;kc++)
          s[i][j] = __builtin_amdgcn_mfma_f32_16x16x32_bf16(qf[i][kc], kf[kc], s[i][j], 0,0,0);
    }
    __builtin_amdgcn_s_setprio(0);

    // scale + causal mask (C/D: row=quad*4+r, col=lane&15)
#pragma unroll
    for (int i=0;i<2;i++)
#pragma unroll
      for (int j=0;j<4;j++)
#pragma unroll
        for (int r=0;r<4;r++){
          int qg = qt*128 + wv*32 + i*16 + lq*4 + r;
          int kg = kt*64 + j*16 + ln;
          float sv = s[i][j][r]*scale;
          s[i][j][r] = (kg > qg) ? -1e30f : sv;
        }

    // online softmax with defer-max (THR=8)
    float mxv[2][4];
#pragma unroll
    for (int i=0;i<2;i++)
#pragma unroll
      for (int r=0;r<4;r++){
        float mx = fmaxf(fmaxf(s[i][0][r], s[i][1][r]), fmaxf(s[i][2][r], s[i][3][r]));
        mx = fmaxf(mx, __shfl_xor(mx, 1));
        mx = fmaxf(mx, __shfl_xor(mx, 2));
        mx = fmaxf(mx, __shfl_xor(mx, 4));
        mx = fmaxf(mx, __shfl_xor(mx, 8));
        mxv[i][r] = mx;
      }
    bool ok = true;
#pragma unroll
    for (int i=0;i<2;i++)
#pragma unroll
      for (int r=0;r<4;r++) ok = ok && (mxv[i][r] <= mi[i][r] + 8.0f);
    if (!__all((int)ok)){
#pragma unroll
      for (int i=0;i<2;i++)
#pragma unroll
        for (int r=0;r<4;r++){
          float mnew = fmaxf(mi[i][r], mxv[i][r]);
          float alpha = __expf(mi[i][r] - mnew);
          li[i][r] *= alpha;
          mi[i][r] = mnew;
#pragma unroll
          for (int jd=0;jd<8;jd++) o[i][jd][r] *= alpha;
        }
    }
#pragma unroll
    for (int i=0;i<2;i++)
#pragma unroll
      for (int r=0;r<4;r++){
        float rs = 0.f;
#pragma unroll
        for (int j=0;j<4;j++){
          float p = __expf(s[i][j][r] - mi[i][r]);   // bounded by e^8
          s[i][j][r] = p; rs += p;
        }
        rs += __shfl_xor(rs, 1); rs += __shfl_xor(rs, 2);
        rs += __shfl_xor(rs, 4); rs += __shfl_xor(rs, 8);
        li[i][r] += rs;
      }

    // P: C-layout -> per-wave LDS strip (swizzled) -> A-layout frags
#pragma unroll
    for (int i=0;i<2;i++)
#pragma unroll
      for (int j=0;j<4;j++)
#pragma unroll
        for (int r=0;r<4;r++){
          const int rr = i*16 + lq*4 + r;
          Ps[wv*2048 + rr*64 + ((j*16 + ln) ^ ((rr & 7) << 3))] = f2b(s[i][j][r]);
        }

    bf16x8 pf[2][2];
#pragma unroll
    for (int i=0;i<2;i++){
      const int prow = i*16 + ln;
      const int psw = (prow & 7) << 3;
#pragma unroll
      for (int kc=0;kc<2;kc++)
        pf[i][kc] = ldfrag(&Ps[wv*2048 + prow*64 + ((kc*32 + lq*8) ^ psw)]);
    }
    __builtin_amdgcn_s_setprio(1);
#pragma unroll
    for (int jd=0;jd<8;jd++){
      const int vrow = jd*16 + ln;
      const int vsw = (vrow & 7) << 3;
#pragma unroll
      for (int kc=0;kc<2;kc++){
        bf16x8 vf = ldfrag(&Vt[vrow*64 + ((kc*32 + lq*8) ^ vsw)]);
#pragma unroll
        for (int i=0;i<2;i++)
          o[i][jd] = __builtin_amdgcn_mfma_f32_16x16x32_bf16(pf[i][kc], vf, o[i][jd], 0,0,0);
      }
    }
    __builtin_amdgcn_s_setprio(0);

    } // active
  }

  // epilogue: y over own Q tile, head-major [BH][T][HD]
#pragma unroll
  for (int i=0;i<2;i++)
#pragma unroll
    for (int r=0;r<4;r++){
      float inv = 1.f / li[i][r];
      int row = qt*128 + wv*32 + i*16 + lq*4 + r;
#pragma unroll
      for (int jd=0;jd<8;jd++)
        qy[((size_t)bh*T_ + row)*HD + jd*16 + ln] = f2b(o[i][jd][r] * inv);
    }
}

extern "C" void kernel_launch(void* const* d_in, const int* in_sizes, int n_in,
                              void* d_out, int out_size, void* d_ws, size_t ws_size,
                              hipStream_t stream)
{
  const float* x      = (const float*)d_in[0];   // [8192][2048] fp32
  const float* W_attn = (const float*)d_in[1];   // [2048][6144] fp32
  const float* b_attn = (const float*)d_in[2];   // [6144] fp32
  const float* W_proj = (const float*)d_in[3];   // [2048][2048] fp32
  const float* b_proj = (const float*)d_in[4];   // [2048] fp32
  float* out = (float*)d_out;                    // [8192][2048] fp32

  u16* Wat = (u16*)d_ws;                         // [6144][2048] bf16 = W_attn^T
  u16* Wpt = Wat + (size_t)6144*2048;            // [2048][2048] bf16 = W_proj^T
  u16* qb  = Wpt + (size_t)2048*2048;            // Q bf16, then y bf16
  u16* xb  = qb  + (size_t)BH*T_*HD;             // x bf16 (only if ws >= 96 MiB)
  u16* kb  = (u16*)d_out;                        // K bf16 (d_out low half)
  u16* vb  = kb + (size_t)BH*T_*HD;              // V bf16 (d_out high half)

  const size_t need = ((size_t)6144*2048 + (size_t)2048*2048
                       + 2*(size_t)BH*T_*HD) * sizeof(u16);   // 96 MiB

  hipLaunchKernelGGL(transpose_cvt, dim3(96,32,1), dim3(256,1,1), 0, stream,
                     W_attn, Wat, 2048, 6144);
  hipLaunchKernelGGL(transpose_cvt, dim3(32,32,1), dim3(256,1,1), 0, stream,
                     W_proj, Wpt, 2048, 2048);
  if (ws_size >= need){
    hipLaunchKernelGGL(cvt_bf16, dim3(1024,1,1), dim3(256,1,1), 0, stream,
                       (const float4*)x, (ushort4*)xb, (B_*T_*C_)/4);
    hipLaunchKernelGGL(gemm_qkv_8p, dim3(768,1,1), dim3(512,1,1), 0, stream,
                       xb, Wat, b_attn, qb, kb, vb);
  } else {
    hipLaunchKernelGGL(gemm_qkv_f32, dim3(48,64,1), dim3(256,1,1), 0, stream,
                       x, Wat, b_attn, qb, kb, vb);
  }
  hipLaunchKernelGGL(attn_fwd, dim3(8,BH,1), dim3(256,1,1), 0, stream,
                     qb, kb, vb);
  hipLaunchKernelGGL(gemm_proj_8p, dim3(256,1,1), dim3(512,1,1), 0, stream,
                     qb, Wpt, b_proj, out);
}